// Round 11
// baseline (208.116 us; speedup 1.0000x reference)
//
#include <hip/hip_runtime.h>

#define DFEAT 128      // D
#define KDIM  256      // 2*D
#define CAP   128      // per-dst CSR slot capacity (Poisson(30) => P(overflow)~1e-48)
#define WSTR  264      // gemm LDS W row stride (bf16): b128 reads 2-way conflict = free
#define ZSTRU 68       // zn-tile LDS row stride (uints): 272 B = 16B-aligned, 2-way = free
#define RTILE 32       // dst rows per fused block

typedef __attribute__((ext_vector_type(8))) short bf16x8;   // 8 bf16 = 4 VGPRs
typedef __attribute__((ext_vector_type(4))) float f32x4;    // MFMA C/D

__device__ __forceinline__ float bflo(unsigned int u) {
    union { unsigned int i; float f; } v; v.i = u << 16; return v.f;
}
__device__ __forceinline__ float bfhi(unsigned int u) {
    union { unsigned int i; float f; } v; v.i = u & 0xffff0000u; return v.f;
}
__device__ __forceinline__ unsigned short f2bf(float f) {
    union { float f; unsigned int i; } v; v.f = f;
    unsigned int r = (v.i + 0x7fffu + ((v.i >> 16) & 1u)) >> 16;  // RNE
    return (unsigned short)r;
}
__device__ __forceinline__ unsigned int pack2(float x, float y) {
    return ((unsigned int)f2bf(y) << 16) | (unsigned int)f2bf(x);
}
__device__ __forceinline__ uint4 cvt8(const float* p) {
    float4 a = *(const float4*)p;
    float4 b = *(const float4*)(p + 4);
    return make_uint4(pack2(a.x, a.y), pack2(a.z, a.w),
                      pack2(b.x, b.y), pack2(b.z, b.w));
}

// ---- fused prep: [append | hconv | Wconv] split by blockIdx range ----------
// Round-7 form (unsharded): best measured. 4 edges/thread => MLP depth 4.
__global__ __launch_bounds__(256) void prep_kernel(
    const float* __restrict__ h, const float* __restrict__ W,
    const int* __restrict__ esrc, const int* __restrict__ edst,
    unsigned short* __restrict__ hbf,        // FAST: [n_src][128]; or null
    unsigned short* __restrict__ z,          // FALLBACK: [n_dst][256]; or null
    unsigned short* __restrict__ Wbf,        // [128][256]
    int* __restrict__ cnt, int* __restrict__ sorted,
    int E, int n_chunks, int B_C, int B_H)
{
    int blk = blockIdx.x;
    int tid = threadIdx.x;
    if (blk < B_C) {
        int e0 = blk * 1024 + tid;
        int d[4], s[4];
        bool ok[4];
        #pragma unroll
        for (int r = 0; r < 4; ++r) {
            int e = e0 + r * 256;
            ok[r] = (e < E);
            d[r] = ok[r] ? edst[e] : 0;
            s[r] = ok[r] ? esrc[e] : 0;
        }
        int pos[4];
        #pragma unroll
        for (int r = 0; r < 4; ++r)
            pos[r] = ok[r] ? atomicAdd(&cnt[d[r]], 1) : CAP;
        #pragma unroll
        for (int r = 0; r < 4; ++r)
            if (ok[r] && pos[r] < CAP)
                sorted[(size_t)d[r] * CAP + pos[r]] = s[r];
    } else if (blk < B_C + B_H) {
        int c0 = (blk - B_C) * 1024 + tid;   // 4 chunks per thread
        #pragma unroll
        for (int r = 0; r < 4; ++r) {
            int t = c0 + r * 256;
            if (t < n_chunks) {
                uint4 v = cvt8(h + (size_t)t * 8);
                if (hbf) {
                    *(uint4*)(hbf + (size_t)t * 8) = v;
                } else {
                    int row = t >> 4;        // 16 chunks per 128-elem row
                    int col = (t & 15) * 8;
                    *(uint4*)(z + (size_t)row * KDIM + col) = v;
                }
            }
        }
    } else {
        int t = (blk - B_C - B_H) * 256 + tid;   // 4096 threads cover 128*256/8
        *(uint4*)(Wbf + (size_t)t * 8) = cvt8(W + (size_t)t * 8);
    }
}

// ---- FUSED agg + MFMA GEMM ------------------------------------------------
// Block = 32 dst rows, 4 waves, 2 blocks/CU (76 KB LDS).
// Phase 1: stage W->LDS; each wave gathers+means 8 dst rows (8-deep MLP)
//          into LDS zn-tile. Phase 2: 2x2 wave split (16 rows x 64 cols),
//          A lo from global hbf, A hi from zn-tile, B from LDS W.
// C/D: col=lane&15, row=(lane>>4)*4+reg. [m89]
__global__ __launch_bounds__(256) void fused_kernel(
    const unsigned short* __restrict__ hbf,   // bf16 [n_src][128]
    const int* __restrict__ cnt,
    const int* __restrict__ sorted,
    const unsigned short* __restrict__ Wbf,   // bf16 [128][256]
    const float* __restrict__ bias,           // f32 [128]
    float* __restrict__ out,                  // f32 [n_dst][128]
    int n_dst)
{
    __shared__ unsigned short Wl[DFEAT][WSTR];   // 67584 B
    __shared__ unsigned int   znl[RTILE][ZSTRU]; // 8704 B

    const int tid  = threadIdx.x;
    const int wave = tid >> 6;
    const int lane = tid & 63;
    const int quad = lane >> 4;
    const int l16  = lane & 15;
    const int m0   = blockIdx.x * RTILE;

    // Stage W: 4096 8-elem chunks, 16 per thread (independent of gather).
    #pragma unroll
    for (int i = 0; i < 16; ++i) {
        int u  = i * 256 + tid;
        int n  = u >> 5;                 // 32 chunks per 256-elem row
        int kq = (u & 31) * 8;
        *(uint4*)&Wl[n][kq] = *(const uint4*)(Wbf + (size_t)n * KDIM + kq);
    }

    // Gather: wave handles local rows wave*8 .. wave*8+7.
    const unsigned int* hp = (const unsigned int*)hbf + lane;  // row = 64 uints
    for (int t = 0; t < 8; ++t) {
        int lr = wave * 8 + t;
        int d  = m0 + lr;
        if (d >= n_dst) break;           // wave-uniform
        int c = cnt[d]; if (c > CAP) c = CAP;
        const int* seg = sorted + (size_t)d * CAP;
        float ax = 0.f, ay = 0.f;
        int i = 0;
        for (; i + 7 < c; i += 8) {
            int ix[8];
            #pragma unroll
            for (int r = 0; r < 8; ++r) ix[r] = seg[i + r];
            unsigned int u[8];
            #pragma unroll
            for (int r = 0; r < 8; ++r) u[r] = hp[(size_t)ix[r] * 64];
            #pragma unroll
            for (int r = 0; r < 8; ++r) { ax += bflo(u[r]); ay += bfhi(u[r]); }
        }
        for (; i + 3 < c; i += 4) {
            int i0 = seg[i],     i1 = seg[i + 1];
            int i2 = seg[i + 2], i3 = seg[i + 3];
            unsigned int u0 = hp[(size_t)i0 * 64], u1 = hp[(size_t)i1 * 64];
            unsigned int u2 = hp[(size_t)i2 * 64], u3 = hp[(size_t)i3 * 64];
            ax += bflo(u0) + bflo(u1) + bflo(u2) + bflo(u3);
            ay += bfhi(u0) + bfhi(u1) + bfhi(u2) + bfhi(u3);
        }
        for (; i < c; ++i) {
            unsigned int u = hp[(size_t)seg[i] * 64];
            ax += bflo(u); ay += bfhi(u);
        }
        float inv = 1.0f / fmaxf((float)c, 1.0f);
        znl[lr][lane] = pack2(ax * inv, ay * inv);
    }
    __syncthreads();

    // MFMA: wave (wave>>1) picks row half, (wave&1) picks col half.
    const int r0 = (wave >> 1) * 16;     // local row base
    const int c0 = (wave & 1) * 64;      // col base
    int m_a = m0 + r0 + l16;
    if (m_a > n_dst - 1) m_a = n_dst - 1;    // clamp: stores guarded below

    f32x4 acc[4];
    #pragma unroll
    for (int ct = 0; ct < 4; ++ct) acc[ct] = (f32x4){0.f, 0.f, 0.f, 0.f};

    const unsigned short* plo = hbf + (size_t)m_a * DFEAT + quad * 8;
    #pragma unroll
    for (int ks = 0; ks < 8; ++ks) {
        bf16x8 a;
        if (ks < 4) {
            a = *(const bf16x8*)(plo + ks * 32);
        } else {
            a = *(const bf16x8*)&znl[r0 + l16][(ks - 4) * 16 + quad * 4];
        }
        #pragma unroll
        for (int ct = 0; ct < 4; ++ct) {
            bf16x8 bb = *(const bf16x8*)&Wl[c0 + ct * 16 + l16][ks * 32 + quad * 8];
            acc[ct] = __builtin_amdgcn_mfma_f32_16x16x32_bf16(a, bb, acc[ct], 0, 0, 0);
        }
    }

    #pragma unroll
    for (int ct = 0; ct < 4; ++ct) {
        int n = c0 + ct * 16 + l16;
        float bc = bias[n];
        #pragma unroll
        for (int r = 0; r < 4; ++r) {
            int m = m0 + r0 + quad * 4 + r;
            if (m < n_dst)
                out[(size_t)m * DFEAT + n] = fmaxf(acc[ct][r] + bc, 0.0f);
        }
    }
}

// ---- FALLBACK path (ws too small): round-7 kernels -------------------------
__global__ __launch_bounds__(256) void agg_f32_kernel(
    const float* __restrict__ h, const int* __restrict__ cnt,
    const int* __restrict__ sorted, unsigned short* __restrict__ z, int n_dst)
{
    int d = blockIdx.x * 4 + (threadIdx.x >> 6);
    if (d >= n_dst) return;
    int lane = threadIdx.x & 63;
    int c = cnt[d]; if (c > CAP) c = CAP;
    const int* seg = sorted + (size_t)d * CAP;
    float ax = 0.f, ay = 0.f;
    const float2* hp = (const float2*)h + lane;                // row = 64 float2
    int i = 0;
    for (; i + 1 < c; i += 2) {
        int i0 = seg[i], i1 = seg[i + 1];
        float2 v0 = hp[(size_t)i0 * 64], v1 = hp[(size_t)i1 * 64];
        ax += v0.x + v1.x; ay += v0.y + v1.y;
    }
    for (; i < c; ++i) {
        float2 v = hp[(size_t)seg[i] * 64];
        ax += v.x; ay += v.y;
    }
    float inv = 1.0f / fmaxf((float)c, 1.0f);
    ((unsigned int*)z)[(size_t)d * 128 + 64 + lane] = pack2(ax * inv, ay * inv);
}

__global__ __launch_bounds__(256) void gemm_kernel(
    const unsigned short* __restrict__ alo, int slo,
    const unsigned short* __restrict__ ahi, int shi,
    const unsigned short* __restrict__ Wbf,
    const float* __restrict__ bias,
    float* __restrict__ out,
    int n_dst)
{
    __shared__ unsigned short Wl[DFEAT][WSTR];
    int tid  = threadIdx.x;
    int wave = tid >> 6;
    int lane = tid & 63;
    int quad = lane >> 4;
    int l16  = lane & 15;
    int m0   = blockIdx.x * 64 + wave * 16;

    #pragma unroll
    for (int i = 0; i < 16; ++i) {
        int u  = i * 256 + tid;
        int n  = u >> 5;
        int kq = (u & 31) * 8;
        *(uint4*)&Wl[n][kq] = *(const uint4*)(Wbf + (size_t)n * KDIM + kq);
    }
    int m_a = m0 + l16;
    if (m_a > n_dst - 1) m_a = n_dst - 1;
    f32x4 acc[8];
    #pragma unroll
    for (int ct = 0; ct < 8; ++ct) acc[ct] = (f32x4){0.f, 0.f, 0.f, 0.f};
    const unsigned short* plo = alo + (size_t)m_a * slo + quad * 8;
    const unsigned short* phi = ahi + (size_t)m_a * shi + quad * 8;
    __syncthreads();
    #pragma unroll
    for (int ks = 0; ks < 8; ++ks) {
        bf16x8 a = (ks < 4) ? *(const bf16x8*)(plo + ks * 32)
                            : *(const bf16x8*)(phi + (ks - 4) * 32);
        #pragma unroll
        for (int ct = 0; ct < 8; ++ct) {
            bf16x8 bb = *(const bf16x8*)&Wl[ct * 16 + l16][ks * 32 + quad * 8];
            acc[ct] = __builtin_amdgcn_mfma_f32_16x16x32_bf16(a, bb, acc[ct], 0, 0, 0);
        }
    }
    #pragma unroll
    for (int ct = 0; ct < 8; ++ct) {
        int n = ct * 16 + l16;
        float bc = bias[n];
        #pragma unroll
        for (int r = 0; r < 4; ++r) {
            int m = m0 + quad * 4 + r;
            if (m < n_dst)
                out[(size_t)m * DFEAT + n] = fmaxf(acc[ct][r] + bc, 0.0f);
        }
    }
}

// ---- launch ----------------------------------------------------------------

extern "C" void kernel_launch(void* const* d_in, const int* in_sizes, int n_in,
                              void* d_out, int out_size, void* d_ws, size_t ws_size,
                              hipStream_t stream) {
    const float* h  = (const float*)d_in[0];
    const int* esrc = (const int*)d_in[1];
    const int* edst = (const int*)d_in[2];
    const float* W  = (const float*)d_in[3];
    const float* b  = (const float*)d_in[4];
    float* out      = (float*)d_out;

    const int E     = in_sizes[1];
    const int n_src = in_sizes[0] / DFEAT;    // 100000
    const int n_dst = out_size / DFEAT;       // 20000

    size_t hbf_bytes  = (size_t)n_src * DFEAT * 2;
    size_t wbf_bytes  = (size_t)DFEAT * KDIM * 2;
    size_t cnt_bytes  = (size_t)n_dst * sizeof(int);
    size_t srt_bytes  = (size_t)n_dst * CAP * sizeof(int);
    bool fast = ws_size >= hbf_bytes + wbf_bytes + cnt_bytes + srt_bytes;

    char* p = (char*)d_ws;
    unsigned short *hbf, *Wbf;
    int *cnt, *sorted;
    if (fast) {
        hbf = (unsigned short*)p;            p += hbf_bytes;
        Wbf = (unsigned short*)p;            p += wbf_bytes;
        cnt = (int*)p;                       p += cnt_bytes;
        sorted = (int*)p;
    } else {
        hbf = nullptr;
        Wbf = (unsigned short*)p;            p += wbf_bytes;
        cnt = (int*)p;                       p += cnt_bytes;
        sorted = (int*)p;
    }

    // FALLBACK: z (bf16 [n_dst][256]) aliases d_out; safe: each gemm wave
    // reads only the rows it later overwrites (verified rounds 3-10).
    unsigned short* z = (unsigned short*)d_out;

    (void)hipMemsetAsync(cnt, 0, cnt_bytes, stream);

    int n_chunks = (fast ? n_src : n_dst) * (DFEAT / 8);
    int B_C = (E + 1023) / 1024;              // 4 edges/thread
    int B_H = (n_chunks + 1023) / 1024;       // 4 chunks/thread
    int B_W = (DFEAT * KDIM / 8) / 256;       // 16
    prep_kernel<<<B_C + B_H + B_W, 256, 0, stream>>>(
        h, W, esrc, edst, hbf, fast ? nullptr : z, Wbf, cnt, sorted,
        E, n_chunks, B_C, B_H);

    if (fast) {
        fused_kernel<<<(n_dst + RTILE - 1) / RTILE, 256, 0, stream>>>(
            hbf, cnt, sorted, Wbf, b, out, n_dst);
    } else {
        agg_f32_kernel<<<(n_dst + 3) / 4, 256, 0, stream>>>(
            h, cnt, sorted, z, n_dst);
        gemm_kernel<<<(n_dst + 63) / 64, 256, 0, stream>>>(
            z, KDIM, z + DFEAT, KDIM, Wbf, b, out, n_dst);
    }
}

// Round 12
// 197.279 us; speedup vs baseline: 1.0549x; 1.0549x over previous
//
#include <hip/hip_runtime.h>

#define DFEAT 128      // D
#define KDIM  256      // 2*D
#define CAP   128      // per-dst CSR slot capacity (Poisson(30) => P(overflow)~1e-48)
#define WSTR  264      // fallback-gemm LDS W row stride
#define ZSTRU 68       // zn-tile LDS row stride (uints): 16B-aligned rows
#define RTILE 32       // dst rows per fused block

typedef __attribute__((ext_vector_type(8))) short bf16x8;   // 8 bf16 = 4 VGPRs
typedef __attribute__((ext_vector_type(4))) float f32x4;    // MFMA C/D

__device__ __forceinline__ float bflo(unsigned int u) {
    union { unsigned int i; float f; } v; v.i = u << 16; return v.f;
}
__device__ __forceinline__ float bfhi(unsigned int u) {
    union { unsigned int i; float f; } v; v.i = u & 0xffff0000u; return v.f;
}
__device__ __forceinline__ unsigned short f2bf(float f) {
    union { float f; unsigned int i; } v; v.f = f;
    unsigned int r = (v.i + 0x7fffu + ((v.i >> 16) & 1u)) >> 16;  // RNE
    return (unsigned short)r;
}
__device__ __forceinline__ unsigned int pack2(float x, float y) {
    return ((unsigned int)f2bf(y) << 16) | (unsigned int)f2bf(x);
}
__device__ __forceinline__ uint4 cvt8(const float* p) {
    float4 a = *(const float4*)p;
    float4 b = *(const float4*)(p + 4);
    return make_uint4(pack2(a.x, a.y), pack2(a.z, a.w),
                      pack2(b.x, b.y), pack2(b.z, b.w));
}

// ---- fused prep: [append | hconv | Wconv] split by blockIdx range ----------
// Unsharded (best measured). 8 edges/thread => 8 independent atomic->store
// chains (MLP depth 8; 4-deep measured 58->50 us, push deeper).
__global__ __launch_bounds__(256) void prep_kernel(
    const float* __restrict__ h, const float* __restrict__ W,
    const int* __restrict__ esrc, const int* __restrict__ edst,
    unsigned short* __restrict__ hbf,        // FAST: [n_src][128]; or null
    unsigned short* __restrict__ z,          // FALLBACK: [n_dst][256]; or null
    unsigned short* __restrict__ Wbf,        // [128][256]
    int* __restrict__ cnt, int* __restrict__ sorted,
    int E, int n_chunks, int B_C, int B_H)
{
    int blk = blockIdx.x;
    int tid = threadIdx.x;
    if (blk < B_C) {
        int e0 = blk * 2048 + tid;
        int d[8], s[8];
        bool ok[8];
        #pragma unroll
        for (int r = 0; r < 8; ++r) {
            int e = e0 + r * 256;
            ok[r] = (e < E);
            d[r] = ok[r] ? edst[e] : 0;
            s[r] = ok[r] ? esrc[e] : 0;
        }
        int pos[8];
        #pragma unroll
        for (int r = 0; r < 8; ++r)
            pos[r] = ok[r] ? atomicAdd(&cnt[d[r]], 1) : CAP;
        #pragma unroll
        for (int r = 0; r < 8; ++r)
            if (ok[r] && pos[r] < CAP)
                sorted[(size_t)d[r] * CAP + pos[r]] = s[r];
    } else if (blk < B_C + B_H) {
        int c0 = (blk - B_C) * 1024 + tid;   // 4 chunks per thread
        #pragma unroll
        for (int r = 0; r < 4; ++r) {
            int t = c0 + r * 256;
            if (t < n_chunks) {
                uint4 v = cvt8(h + (size_t)t * 8);
                if (hbf) {
                    *(uint4*)(hbf + (size_t)t * 8) = v;
                } else {
                    int row = t >> 4;        // 16 chunks per 128-elem row
                    int col = (t & 15) * 8;
                    *(uint4*)(z + (size_t)row * KDIM + col) = v;
                }
            }
        }
    } else {
        int t = (blk - B_C - B_H) * 256 + tid;   // 4096 threads cover 128*256/8
        *(uint4*)(Wbf + (size_t)t * 8) = cvt8(W + (size_t)t * 8);
    }
}

// ---- FUSED agg + MFMA GEMM, LDS-light -------------------------------------
// Round-11 failure: 76 KB LDS (W tile) -> 1 block/CU -> 12.5% occupancy
// strangled the latency-bound gather. Fix: only the 8.7 KB zn-tile lives in
// LDS; B-fragments read from global Wbf (64 KB, L2-resident; rounds 7 vs
// 9/10 showed W-source is ~neutral for the gemm). Occupancy -> VGPR-bound.
// Block = 32 dst rows, 4 waves. Phase 1: wave w gathers rows w*8..w*8+7
// (8-deep MLP) -> znl. Phase 2: 2x2 wave split (16 rows x 64 cols);
// A lo from hbf, A hi from znl, B from global.
// C/D: col=lane&15, row=(lane>>4)*4+reg. [m89]
__global__ __launch_bounds__(256) void fused_kernel(
    const unsigned short* __restrict__ hbf,   // bf16 [n_src][128]
    const int* __restrict__ cnt,
    const int* __restrict__ sorted,
    const unsigned short* __restrict__ Wbf,   // bf16 [128][256]
    const float* __restrict__ bias,           // f32 [128]
    float* __restrict__ out,                  // f32 [n_dst][128]
    int n_dst)
{
    __shared__ unsigned int znl[RTILE][ZSTRU];   // 8704 B — only LDS use

    const int tid  = threadIdx.x;
    const int wave = tid >> 6;
    const int lane = tid & 63;
    const int quad = lane >> 4;
    const int l16  = lane & 15;
    const int m0   = blockIdx.x * RTILE;

    // Gather: wave handles local rows wave*8 .. wave*8+7.
    const unsigned int* hp = (const unsigned int*)hbf + lane;  // row = 64 uints
    for (int t = 0; t < 8; ++t) {
        int lr = wave * 8 + t;
        int d  = m0 + lr;
        if (d >= n_dst) break;           // wave-uniform
        int c = cnt[d]; if (c > CAP) c = CAP;
        const int* seg = sorted + (size_t)d * CAP;
        float ax = 0.f, ay = 0.f;
        int i = 0;
        for (; i + 7 < c; i += 8) {
            int ix[8];
            #pragma unroll
            for (int r = 0; r < 8; ++r) ix[r] = seg[i + r];
            unsigned int u[8];
            #pragma unroll
            for (int r = 0; r < 8; ++r) u[r] = hp[(size_t)ix[r] * 64];
            #pragma unroll
            for (int r = 0; r < 8; ++r) { ax += bflo(u[r]); ay += bfhi(u[r]); }
        }
        for (; i + 3 < c; i += 4) {
            int i0 = seg[i],     i1 = seg[i + 1];
            int i2 = seg[i + 2], i3 = seg[i + 3];
            unsigned int u0 = hp[(size_t)i0 * 64], u1 = hp[(size_t)i1 * 64];
            unsigned int u2 = hp[(size_t)i2 * 64], u3 = hp[(size_t)i3 * 64];
            ax += bflo(u0) + bflo(u1) + bflo(u2) + bflo(u3);
            ay += bfhi(u0) + bfhi(u1) + bfhi(u2) + bfhi(u3);
        }
        for (; i < c; ++i) {
            unsigned int u = hp[(size_t)seg[i] * 64];
            ax += bflo(u); ay += bfhi(u);
        }
        float inv = 1.0f / fmaxf((float)c, 1.0f);
        znl[lr][lane] = pack2(ax * inv, ay * inv);
    }
    __syncthreads();

    // MFMA: wave (wave>>1) picks row half, (wave&1) picks col half.
    const int r0 = (wave >> 1) * 16;     // local row base
    const int c0 = (wave & 1) * 64;      // col base
    int m_a = m0 + r0 + l16;
    if (m_a > n_dst - 1) m_a = n_dst - 1;    // clamp: stores guarded below

    f32x4 acc[4];
    #pragma unroll
    for (int ct = 0; ct < 4; ++ct) acc[ct] = (f32x4){0.f, 0.f, 0.f, 0.f};

    const unsigned short* plo = hbf + (size_t)m_a * DFEAT + quad * 8;
    const unsigned short* pW  = Wbf + (size_t)(c0 + l16) * KDIM + quad * 8;
    #pragma unroll
    for (int ks = 0; ks < 8; ++ks) {
        bf16x8 a;
        if (ks < 4) {
            a = *(const bf16x8*)(plo + ks * 32);
        } else {
            a = *(const bf16x8*)&znl[r0 + l16][(ks - 4) * 16 + quad * 4];
        }
        #pragma unroll
        for (int ct = 0; ct < 4; ++ct) {
            bf16x8 bb = *(const bf16x8*)(pW + (size_t)ct * 16 * KDIM + ks * 32);
            acc[ct] = __builtin_amdgcn_mfma_f32_16x16x32_bf16(a, bb, acc[ct], 0, 0, 0);
        }
    }

    #pragma unroll
    for (int ct = 0; ct < 4; ++ct) {
        int n = c0 + ct * 16 + l16;
        float bc = bias[n];
        #pragma unroll
        for (int r = 0; r < 4; ++r) {
            int m = m0 + r0 + quad * 4 + r;
            if (m < n_dst)
                out[(size_t)m * DFEAT + n] = fmaxf(acc[ct][r] + bc, 0.0f);
        }
    }
}

// ---- FALLBACK path (ws too small): round-7 kernels -------------------------
__global__ __launch_bounds__(256) void agg_f32_kernel(
    const float* __restrict__ h, const int* __restrict__ cnt,
    const int* __restrict__ sorted, unsigned short* __restrict__ z, int n_dst)
{
    int d = blockIdx.x * 4 + (threadIdx.x >> 6);
    if (d >= n_dst) return;
    int lane = threadIdx.x & 63;
    int c = cnt[d]; if (c > CAP) c = CAP;
    const int* seg = sorted + (size_t)d * CAP;
    float ax = 0.f, ay = 0.f;
    const float2* hp = (const float2*)h + lane;                // row = 64 float2
    int i = 0;
    for (; i + 1 < c; i += 2) {
        int i0 = seg[i], i1 = seg[i + 1];
        float2 v0 = hp[(size_t)i0 * 64], v1 = hp[(size_t)i1 * 64];
        ax += v0.x + v1.x; ay += v0.y + v1.y;
    }
    for (; i < c; ++i) {
        float2 v = hp[(size_t)seg[i] * 64];
        ax += v.x; ay += v.y;
    }
    float inv = 1.0f / fmaxf((float)c, 1.0f);
    ((unsigned int*)z)[(size_t)d * 128 + 64 + lane] = pack2(ax * inv, ay * inv);
}

__global__ __launch_bounds__(256) void gemm_kernel(
    const unsigned short* __restrict__ alo, int slo,
    const unsigned short* __restrict__ ahi, int shi,
    const unsigned short* __restrict__ Wbf,
    const float* __restrict__ bias,
    float* __restrict__ out,
    int n_dst)
{
    __shared__ unsigned short Wl[DFEAT][WSTR];
    int tid  = threadIdx.x;
    int wave = tid >> 6;
    int lane = tid & 63;
    int quad = lane >> 4;
    int l16  = lane & 15;
    int m0   = blockIdx.x * 64 + wave * 16;

    #pragma unroll
    for (int i = 0; i < 16; ++i) {
        int u  = i * 256 + tid;
        int n  = u >> 5;
        int kq = (u & 31) * 8;
        *(uint4*)&Wl[n][kq] = *(const uint4*)(Wbf + (size_t)n * KDIM + kq);
    }
    int m_a = m0 + l16;
    if (m_a > n_dst - 1) m_a = n_dst - 1;
    f32x4 acc[8];
    #pragma unroll
    for (int ct = 0; ct < 8; ++ct) acc[ct] = (f32x4){0.f, 0.f, 0.f, 0.f};
    const unsigned short* plo = alo + (size_t)m_a * slo + quad * 8;
    const unsigned short* phi = ahi + (size_t)m_a * shi + quad * 8;
    __syncthreads();
    #pragma unroll
    for (int ks = 0; ks < 8; ++ks) {
        bf16x8 a = (ks < 4) ? *(const bf16x8*)(plo + ks * 32)
                            : *(const bf16x8*)(phi + (ks - 4) * 32);
        #pragma unroll
        for (int ct = 0; ct < 8; ++ct) {
            bf16x8 bb = *(const bf16x8*)&Wl[ct * 16 + l16][ks * 32 + quad * 8];
            acc[ct] = __builtin_amdgcn_mfma_f32_16x16x32_bf16(a, bb, acc[ct], 0, 0, 0);
        }
    }
    #pragma unroll
    for (int ct = 0; ct < 8; ++ct) {
        int n = ct * 16 + l16;
        float bc = bias[n];
        #pragma unroll
        for (int r = 0; r < 4; ++r) {
            int m = m0 + quad * 4 + r;
            if (m < n_dst)
                out[(size_t)m * DFEAT + n] = fmaxf(acc[ct][r] + bc, 0.0f);
        }
    }
}

// ---- launch ----------------------------------------------------------------

extern "C" void kernel_launch(void* const* d_in, const int* in_sizes, int n_in,
                              void* d_out, int out_size, void* d_ws, size_t ws_size,
                              hipStream_t stream) {
    const float* h  = (const float*)d_in[0];
    const int* esrc = (const int*)d_in[1];
    const int* edst = (const int*)d_in[2];
    const float* W  = (const float*)d_in[3];
    const float* b  = (const float*)d_in[4];
    float* out      = (float*)d_out;

    const int E     = in_sizes[1];
    const int n_src = in_sizes[0] / DFEAT;    // 100000
    const int n_dst = out_size / DFEAT;       // 20000

    size_t hbf_bytes  = (size_t)n_src * DFEAT * 2;
    size_t wbf_bytes  = (size_t)DFEAT * KDIM * 2;
    size_t cnt_bytes  = (size_t)n_dst * sizeof(int);
    size_t srt_bytes  = (size_t)n_dst * CAP * sizeof(int);
    bool fast = ws_size >= hbf_bytes + wbf_bytes + cnt_bytes + srt_bytes;

    char* p = (char*)d_ws;
    unsigned short *hbf, *Wbf;
    int *cnt, *sorted;
    if (fast) {
        hbf = (unsigned short*)p;            p += hbf_bytes;
        Wbf = (unsigned short*)p;            p += wbf_bytes;
        cnt = (int*)p;                       p += cnt_bytes;
        sorted = (int*)p;
    } else {
        hbf = nullptr;
        Wbf = (unsigned short*)p;            p += wbf_bytes;
        cnt = (int*)p;                       p += cnt_bytes;
        sorted = (int*)p;
    }

    // FALLBACK: z (bf16 [n_dst][256]) aliases d_out; safe: each gemm wave
    // reads only the rows it later overwrites (verified rounds 3-11).
    unsigned short* z = (unsigned short*)d_out;

    (void)hipMemsetAsync(cnt, 0, cnt_bytes, stream);

    int n_chunks = (fast ? n_src : n_dst) * (DFEAT / 8);
    int B_C = (E + 2047) / 2048;              // 8 edges/thread
    int B_H = (n_chunks + 1023) / 1024;       // 4 chunks/thread
    int B_W = (DFEAT * KDIM / 8) / 256;       // 16
    prep_kernel<<<B_C + B_H + B_W, 256, 0, stream>>>(
        h, W, esrc, edst, hbf, fast ? nullptr : z, Wbf, cnt, sorted,
        E, n_chunks, B_C, B_H);

    if (fast) {
        fused_kernel<<<(n_dst + RTILE - 1) / RTILE, 256, 0, stream>>>(
            hbf, cnt, sorted, Wbf, b, out, n_dst);
    } else {
        agg_f32_kernel<<<(n_dst + 3) / 4, 256, 0, stream>>>(
            h, cnt, sorted, z, n_dst);
        gemm_kernel<<<(n_dst + 63) / 64, 256, 0, stream>>>(
            z, KDIM, z + DFEAT, KDIM, Wbf, b, out, n_dst);
    }
}

// Round 13
// 167.955 us; speedup vs baseline: 1.2391x; 1.1746x over previous
//
#include <hip/hip_runtime.h>

#define DFEAT 128      // D
#define KDIM  256      // 2*D
#define CAP   128      // per-dst CSR slot capacity (Poisson(30) => P(overflow)~1e-48)
#define WSTR  264      // gemm LDS W row stride (bf16): b128 reads 2-way conflict = free

typedef __attribute__((ext_vector_type(8))) short bf16x8;   // 8 bf16 = 4 VGPRs
typedef __attribute__((ext_vector_type(4))) float f32x4;    // MFMA C/D

__device__ __forceinline__ float bflo(unsigned int u) {
    union { unsigned int i; float f; } v; v.i = u << 16; return v.f;
}
__device__ __forceinline__ float bfhi(unsigned int u) {
    union { unsigned int i; float f; } v; v.i = u & 0xffff0000u; return v.f;
}
__device__ __forceinline__ unsigned short f2bf(float f) {
    union { float f; unsigned int i; } v; v.f = f;
    unsigned int r = (v.i + 0x7fffu + ((v.i >> 16) & 1u)) >> 16;  // RNE
    return (unsigned short)r;
}
__device__ __forceinline__ unsigned int pack2(float x, float y) {
    return ((unsigned int)f2bf(y) << 16) | (unsigned int)f2bf(x);
}
__device__ __forceinline__ uint4 cvt8(const float* p) {
    float4 a = *(const float4*)p;
    float4 b = *(const float4*)(p + 4);
    return make_uint4(pack2(a.x, a.y), pack2(a.z, a.w),
                      pack2(b.x, b.y), pack2(b.z, b.w));
}

// ---- fused prep: [append | hconv | Wconv] split by blockIdx range ----------
// Round-7 form exactly: 4 edges/thread (MLP 4; 8-deep regressed in R12),
// unsharded (XCD sharding bought nothing in R8/R10).
__global__ __launch_bounds__(256) void prep_kernel(
    const float* __restrict__ h, const float* __restrict__ W,
    const int* __restrict__ esrc, const int* __restrict__ edst,
    unsigned short* __restrict__ hbf,        // FAST: [n_src][128]; or null
    unsigned short* __restrict__ z,          // FALLBACK: [n_dst][256]; or null
    unsigned short* __restrict__ Wbf,        // [128][256]
    int* __restrict__ cnt, int* __restrict__ sorted,
    int E, int n_chunks, int B_C, int B_H)
{
    int blk = blockIdx.x;
    int tid = threadIdx.x;
    if (blk < B_C) {
        int e0 = blk * 1024 + tid;
        int d[4], s[4];
        bool ok[4];
        #pragma unroll
        for (int r = 0; r < 4; ++r) {
            int e = e0 + r * 256;
            ok[r] = (e < E);
            d[r] = ok[r] ? edst[e] : 0;
            s[r] = ok[r] ? esrc[e] : 0;
        }
        int pos[4];
        #pragma unroll
        for (int r = 0; r < 4; ++r)
            pos[r] = ok[r] ? atomicAdd(&cnt[d[r]], 1) : CAP;
        #pragma unroll
        for (int r = 0; r < 4; ++r)
            if (ok[r] && pos[r] < CAP)
                sorted[(size_t)d[r] * CAP + pos[r]] = s[r];
    } else if (blk < B_C + B_H) {
        int c0 = (blk - B_C) * 1024 + tid;   // 4 chunks per thread
        #pragma unroll
        for (int r = 0; r < 4; ++r) {
            int t = c0 + r * 256;
            if (t < n_chunks) {
                uint4 v = cvt8(h + (size_t)t * 8);
                if (hbf) {
                    *(uint4*)(hbf + (size_t)t * 8) = v;
                } else {
                    int row = t >> 4;        // 16 chunks per 128-elem row
                    int col = (t & 15) * 8;
                    *(uint4*)(z + (size_t)row * KDIM + col) = v;
                }
            }
        }
    } else {
        int t = (blk - B_C - B_H) * 256 + tid;   // 4096 threads cover 128*256/8
        *(uint4*)(Wbf + (size_t)t * 8) = cvt8(W + (size_t)t * 8);
    }
}

// ---- aggregation: TWO dsts per wave (half-wave each), 8-deep MLP -----------
// Each half-wave (32 lanes x 8 B) covers one 256 B bf16 row; 8-deep unroll
// gives 16 outstanding row-gathers per wave (2x round-7's MLP).
__global__ __launch_bounds__(256) void agg_bf16_kernel(
    const unsigned short* __restrict__ hbf, const int* __restrict__ cnt,
    const int* __restrict__ sorted, unsigned short* __restrict__ zn, int n_dst)
{
    int wave = threadIdx.x >> 6;
    int lane = threadIdx.x & 63;
    int half = lane >> 5;                    // 0/1: which dst
    int l32  = lane & 31;
    int d = blockIdx.x * 8 + wave * 2 + half;

    int c = (d < n_dst) ? cnt[d] : 0;
    if (c > CAP) c = CAP;
    const int* seg = sorted + (size_t)d * CAP;

    float ax = 0.f, ay = 0.f, az = 0.f, aw = 0.f;
    const uint2* hp = (const uint2*)hbf + l32;   // row = 32 uint2 (256 B)
    int i = 0;
    for (; i + 7 < c; i += 8) {
        int ix[8];
        #pragma unroll
        for (int r = 0; r < 8; ++r) ix[r] = seg[i + r];
        uint2 u[8];
        #pragma unroll
        for (int r = 0; r < 8; ++r) u[r] = hp[(size_t)ix[r] * 32];
        #pragma unroll
        for (int r = 0; r < 8; ++r) {
            ax += bflo(u[r].x); ay += bfhi(u[r].x);
            az += bflo(u[r].y); aw += bfhi(u[r].y);
        }
    }
    for (; i + 3 < c; i += 4) {
        int i0 = seg[i],     i1 = seg[i + 1];
        int i2 = seg[i + 2], i3 = seg[i + 3];
        uint2 u0 = hp[(size_t)i0 * 32], u1 = hp[(size_t)i1 * 32];
        uint2 u2 = hp[(size_t)i2 * 32], u3 = hp[(size_t)i3 * 32];
        ax += bflo(u0.x) + bflo(u1.x) + bflo(u2.x) + bflo(u3.x);
        ay += bfhi(u0.x) + bfhi(u1.x) + bfhi(u2.x) + bfhi(u3.x);
        az += bflo(u0.y) + bflo(u1.y) + bflo(u2.y) + bflo(u3.y);
        aw += bfhi(u0.y) + bfhi(u1.y) + bfhi(u2.y) + bfhi(u3.y);
    }
    for (; i < c; ++i) {
        uint2 u = hp[(size_t)seg[i] * 32];
        ax += bflo(u.x); ay += bfhi(u.x);
        az += bflo(u.y); aw += bfhi(u.y);
    }
    float inv = 1.0f / fmaxf((float)c, 1.0f);
    if (d < n_dst)
        ((uint2*)zn)[(size_t)d * 32 + l32] =
            make_uint2(pack2(ax * inv, ay * inv), pack2(az * inv, aw * inv));
}

// FALLBACK: gather f32 rows, write into z [n_dst][256] high half.
__global__ __launch_bounds__(256) void agg_f32_kernel(
    const float* __restrict__ h, const int* __restrict__ cnt,
    const int* __restrict__ sorted, unsigned short* __restrict__ z, int n_dst)
{
    int d = blockIdx.x * 4 + (threadIdx.x >> 6);
    if (d >= n_dst) return;
    int lane = threadIdx.x & 63;
    int c = cnt[d]; if (c > CAP) c = CAP;
    const int* seg = sorted + (size_t)d * CAP;
    float ax = 0.f, ay = 0.f;
    const float2* hp = (const float2*)h + lane;                // row = 64 float2
    int i = 0;
    for (; i + 1 < c; i += 2) {
        int i0 = seg[i], i1 = seg[i + 1];
        float2 v0 = hp[(size_t)i0 * 64], v1 = hp[(size_t)i1 * 64];
        ax += v0.x + v1.x; ay += v0.y + v1.y;
    }
    for (; i < c; ++i) {
        float2 v = hp[(size_t)seg[i] * 64];
        ax += v.x; ay += v.y;
    }
    float inv = 1.0f / fmaxf((float)c, 1.0f);
    ((unsigned int*)z)[(size_t)d * 128 + 64 + lane] = pack2(ax * inv, ay * inv);
}

// ---- MFMA GEMM with W staged in LDS (round-10 form) ------------------------
// Wave = 16 rows x 128 cols. C/D: col=lane&15, row=(lane>>4)*4+reg. [m89]
__global__ __launch_bounds__(256) void gemm_kernel(
    const unsigned short* __restrict__ alo, int slo,
    const unsigned short* __restrict__ ahi, int shi,
    const unsigned short* __restrict__ Wbf,   // bf16 [128][256]
    const float* __restrict__ bias,           // f32 [128]
    float* __restrict__ out,                  // f32 [n_dst][128]
    int n_dst)
{
    __shared__ unsigned short Wl[DFEAT][WSTR];   // 67584 B

    int tid  = threadIdx.x;
    int wave = tid >> 6;
    int lane = tid & 63;
    int quad = lane >> 4;
    int l16  = lane & 15;
    int m0   = blockIdx.x * 64 + wave * 16;

    #pragma unroll
    for (int i = 0; i < 16; ++i) {
        int u  = i * 256 + tid;
        int n  = u >> 5;                 // 32 chunks per 256-elem row
        int kq = (u & 31) * 8;
        *(uint4*)&Wl[n][kq] = *(const uint4*)(Wbf + (size_t)n * KDIM + kq);
    }

    int m_a = m0 + l16;
    if (m_a > n_dst - 1) m_a = n_dst - 1;     // clamp: stores guarded below

    f32x4 acc[8];
    #pragma unroll
    for (int ct = 0; ct < 8; ++ct) acc[ct] = (f32x4){0.f, 0.f, 0.f, 0.f};

    const unsigned short* plo = alo + (size_t)m_a * slo + quad * 8;
    const unsigned short* phi = ahi + (size_t)m_a * shi + quad * 8;

    __syncthreads();

    #pragma unroll
    for (int ks = 0; ks < 8; ++ks) {
        bf16x8 a = (ks < 4) ? *(const bf16x8*)(plo + ks * 32)
                            : *(const bf16x8*)(phi + (ks - 4) * 32);
        #pragma unroll
        for (int ct = 0; ct < 8; ++ct) {
            bf16x8 bb = *(const bf16x8*)&Wl[ct * 16 + l16][ks * 32 + quad * 8];
            acc[ct] = __builtin_amdgcn_mfma_f32_16x16x32_bf16(a, bb, acc[ct], 0, 0, 0);
        }
    }

    #pragma unroll
    for (int ct = 0; ct < 8; ++ct) {
        int n = ct * 16 + l16;
        float bc = bias[n];
        #pragma unroll
        for (int r = 0; r < 4; ++r) {
            int m = m0 + quad * 4 + r;
            if (m < n_dst)
                out[(size_t)m * DFEAT + n] = fmaxf(acc[ct][r] + bc, 0.0f);
        }
    }
}

// ---- launch ----------------------------------------------------------------

extern "C" void kernel_launch(void* const* d_in, const int* in_sizes, int n_in,
                              void* d_out, int out_size, void* d_ws, size_t ws_size,
                              hipStream_t stream) {
    const float* h  = (const float*)d_in[0];
    const int* esrc = (const int*)d_in[1];
    const int* edst = (const int*)d_in[2];
    const float* W  = (const float*)d_in[3];
    const float* b  = (const float*)d_in[4];
    float* out      = (float*)d_out;

    const int E     = in_sizes[1];
    const int n_src = in_sizes[0] / DFEAT;    // 100000
    const int n_dst = out_size / DFEAT;       // 20000

    size_t hbf_bytes  = (size_t)n_src * DFEAT * 2;
    size_t zn_bytes   = (size_t)n_dst * DFEAT * 2;
    size_t wbf_bytes  = (size_t)DFEAT * KDIM * 2;
    size_t cnt_bytes  = (size_t)n_dst * sizeof(int);
    size_t srt_bytes  = (size_t)n_dst * CAP * sizeof(int);
    bool fast = ws_size >= hbf_bytes + zn_bytes + wbf_bytes + cnt_bytes + srt_bytes;

    char* p = (char*)d_ws;
    unsigned short *hbf, *zn, *Wbf;
    int *cnt, *sorted;
    if (fast) {
        hbf = (unsigned short*)p;            p += hbf_bytes;
        zn  = (unsigned short*)p;            p += zn_bytes;
        Wbf = (unsigned short*)p;            p += wbf_bytes;
        cnt = (int*)p;                       p += cnt_bytes;
        sorted = (int*)p;
    } else {
        hbf = nullptr; zn = nullptr;
        Wbf = (unsigned short*)p;            p += wbf_bytes;
        cnt = (int*)p;                       p += cnt_bytes;
        sorted = (int*)p;
    }

    // FALLBACK: z (bf16 [n_dst][256]) aliases d_out; safe: each gemm wave
    // reads only the rows it later overwrites (verified rounds 3-12).
    unsigned short* z = (unsigned short*)d_out;

    (void)hipMemsetAsync(cnt, 0, cnt_bytes, stream);

    int n_chunks = (fast ? n_src : n_dst) * (DFEAT / 8);
    int B_C = (E + 1023) / 1024;              // 4 edges/thread
    int B_H = (n_chunks + 1023) / 1024;       // 4 chunks/thread
    int B_W = (DFEAT * KDIM / 8) / 256;       // 16
    prep_kernel<<<B_C + B_H + B_W, 256, 0, stream>>>(
        h, W, esrc, edst, hbf, fast ? nullptr : z, Wbf, cnt, sorted,
        E, n_chunks, B_C, B_H);

    if (fast) {
        agg_bf16_kernel<<<(n_dst + 7) / 8, 256, 0, stream>>>(
            hbf, cnt, sorted, zn, n_dst);
        gemm_kernel<<<(n_dst + 63) / 64, 256, 0, stream>>>(
            hbf, DFEAT, zn, DFEAT, Wbf, b, out, n_dst);
    } else {
        agg_f32_kernel<<<(n_dst + 3) / 4, 256, 0, stream>>>(
            h, cnt, sorted, z, n_dst);
        gemm_kernel<<<(n_dst + 63) / 64, 256, 0, stream>>>(
            z, KDIM, z + DFEAT, KDIM, Wbf, b, out, n_dst);
    }
}